// Round 5
// baseline (58.110 us; speedup 1.0000x reference)
//
#include <hip/hip_runtime.h>

constexpr int C = 26;                        // floats per cell
constexpr int THREADS = 256;                 // 4 waves
constexpr int WAVE_ROWS = 64;                // one row per lane
constexpr int WAVE_FLOATS = WAVE_ROWS * C;   // 1664 floats = 6656 B per input per wave
constexpr int BLOCK_ROWS = 4 * WAVE_ROWS;    // 256 rows per block
constexpr float LAMBDA_LOC = 10.0f;
constexpr float LAMBDA_NOOBJ = 0.5f;

__device__ __forceinline__ void stage16(const float* g, float* lds_uniform) {
    // width-16: per-lane global src, wave-uniform LDS dst (HW adds lane*16B)
    __builtin_amdgcn_global_load_lds(
        (const __attribute__((address_space(1))) unsigned int*)g,
        (__attribute__((address_space(3))) unsigned int*)lds_uniform,
        16, 0, 0);
}
__device__ __forceinline__ void stage4(const float* g, float* lds_uniform) {
    // width-4: per-lane global src, wave-uniform LDS dst (HW adds lane*4B)
    __builtin_amdgcn_global_load_lds(
        (const __attribute__((address_space(1))) unsigned int*)g,
        (__attribute__((address_space(3))) unsigned int*)lds_uniform,
        4, 0, 0);
}

__device__ __forceinline__ float iou_f(float b1x, float b1y, float b1w, float b1h,
                                       float b2x, float b2y, float b2w, float b2h) {
    float cx1 = b1x * 64.f, cy1 = b1y * 64.f, hw1 = b1w * 224.f, hh1 = b1h * 224.f;
    float l1 = cx1 - hw1, t1 = cy1 - hh1, r1 = cx1 + hw1, bo1 = cy1 + hh1;
    float cx2 = b2x * 64.f, cy2 = b2y * 64.f, hw2 = b2w * 224.f, hh2 = b2h * 224.f;
    float l2 = cx2 - hw2, t2 = cy2 - hh2, r2 = cx2 + hw2, bo2 = cy2 + hh2;
    float xA = fmaxf(l1, l2), yA = fmaxf(t1, t2);
    float xB = fminf(r1, r2), yB = fminf(bo1, bo2);
    float iw = fmaxf(0.f, xB - xA + 1.f);
    float ih = fmaxf(0.f, yB - yA + 1.f);
    float inter = iw * ih;
    float a1 = (r1 - l1 + 1.f) * (bo1 - t1 + 1.f);
    float a2 = (r2 - l2 + 1.f) * (bo2 - t2 + 1.f);
    return inter / (a1 + a2 - inter);
}

__device__ __forceinline__ float row_loss(const float* lds_p, const float* lds_t, int row) {
    const float2* pr = reinterpret_cast<const float2*>(lds_p + row * C);
    const float2* tr = reinterpret_cast<const float2*>(lds_t + row * C);

    float2 p01 = pr[0], p23 = pr[1], p45 = pr[2], p67 = pr[3], p89 = pr[4];
    float2 t01 = tr[0], t23 = tr[1], t45 = tr[2], t67 = tr[3], t89 = tr[4];

    float cls = 0.f;
    #pragma unroll
    for (int j = 5; j < 13; ++j) {
        float2 a = pr[j], b = tr[j];
        float dx = a.x - b.x, dy = a.y - b.y;
        cls = fmaf(dx, dx, cls);
        cls = fmaf(dy, dy, cls);
    }

    float obj   = t45.x;
    float noobj = 1.f - obj;

    float iou1 = iou_f(p01.x, p01.y, p23.x, p23.y, t01.x, t01.y, t23.x, t23.y);
    float iou2 = iou_f(p45.y, p67.x, p67.y, p89.x, t01.x, t01.y, t23.x, t23.y);

    bool  best2 = iou2 > iou1;
    float iou_m = best2 ? iou2 : iou1;

    float vpx = best2 ? p45.y : p01.x;
    float vpy = best2 ? p67.x : p01.y;
    float vpw = best2 ? p67.y : p23.x;
    float vph = best2 ? p89.x : p23.y;
    float vpc = best2 ? p89.y : p45.x;
    float vtx = best2 ? t45.y : t01.x;
    float vty = best2 ? t67.x : t01.y;
    float vtw = best2 ? t67.y : t23.x;
    float vth = best2 ? t89.x : t23.y;

    float dx = vpx - vtx, dy = vpy - vty;
    float xy = dx * dx + dy * dy;
    float sw = sqrtf(vpw) - sqrtf(vtw);
    float sh = sqrtf(vph) - sqrtf(vth);
    float wh = sw * sw + sh * sh;
    float dc = vpc - iou_m;
    float oc = dc * dc;
    float d1 = p45.x - t45.x;
    float d2 = p89.y - t89.y;

    return obj * (LAMBDA_LOC * (xy + wh) + oc + 2.f * cls)
         + LAMBDA_NOOBJ * noobj * (d1 * d1 + d2 * d2);
}

// Wave-private staging: wave w stages and consumes exactly its own 64 rows.
// No __syncthreads between staging and compute — only wave-level vmcnt(0).
// rows must be a multiple of BLOCK_ROWS (802816 = 3136*256).
__global__ __launch_bounds__(THREADS) void yolo_main(
    const float* __restrict__ pred, const float* __restrict__ targ,
    float* __restrict__ out)
{
    __shared__ float lp[4][WAVE_FLOATS];
    __shared__ float lt[4][WAVE_FLOATS];

    const int tid  = threadIdx.x;
    const int wid  = tid >> 6;
    const int lane = tid & 63;

    const size_t wave_base = ((size_t)blockIdx.x * 4 + wid) * WAVE_FLOATS;
    const float* pw = pred + wave_base;
    const float* tw = targ + wave_base;

    // ---- stage this wave's 64 rows (6656 B per input) ----
    // 6 full width-16 chunks: floats [0, 1536)
    #pragma unroll
    for (int k = 0; k < 6; ++k) {
        int src = (k * 64 + lane) * 4;         // per-lane float index
        stage16(pw + src, &lp[wid][k * 256]);  // wave-uniform dst
        stage16(tw + src, &lt[wid][k * 256]);
    }
    // tail floats [1536, 1664): 2 width-4 rounds, full wave each
    #pragma unroll
    for (int m = 0; m < 2; ++m) {
        int src = 1536 + m * 64 + lane;
        stage4(pw + src, &lp[wid][1536 + m * 64]);
        stage4(tw + src, &lt[wid][1536 + m * 64]);
    }

    // wave-level completion: wait only this wave's 16 loads, no block barrier
    asm volatile("s_waitcnt vmcnt(0)" ::: "memory");
    __builtin_amdgcn_sched_barrier(0);

    // ---- compute: lane owns row `lane` of its wave's region ----
    float acc = row_loss(lp[wid], lt[wid], lane);

    // ---- reduce: wave shuffle -> one barrier -> one atomic per block ----
    #pragma unroll
    for (int off = 32; off > 0; off >>= 1)
        acc += __shfl_down(acc, off);

    __shared__ float wsum[4];
    if (lane == 0) wsum[wid] = acc;
    __syncthreads();
    if (tid == 0)
        atomicAdd(out, wsum[0] + wsum[1] + wsum[2] + wsum[3]);
}

extern "C" void kernel_launch(void* const* d_in, const int* in_sizes, int n_in,
                              void* d_out, int out_size, void* d_ws, size_t ws_size,
                              hipStream_t stream) {
    const float* pred = (const float*)d_in[0];
    const float* targ = (const float*)d_in[1];
    float* out = (float*)d_out;
    int rows = in_sizes[0] / C;              // 802816
    int n_blocks = rows / BLOCK_ROWS;        // 3136 (exact)

    hipMemsetAsync(out, 0, sizeof(float), stream);   // zero accumulator (capture-safe)
    yolo_main<<<n_blocks, THREADS, 0, stream>>>(pred, targ, out);
}

// Round 6
// 31.196 us; speedup vs baseline: 1.8627x; 1.8627x over previous
//
#include <hip/hip_runtime.h>

constexpr int C = 26;                        // floats per cell
constexpr int THREADS = 256;                 // 4 waves
constexpr int WAVE_ROWS = 64;                // one row per lane
constexpr int WAVE_FLOATS = WAVE_ROWS * C;   // 1664 floats = 6656 B per input per wave
constexpr int BLOCK_ROWS = 4 * WAVE_ROWS;    // 256 rows per block
constexpr float LAMBDA_LOC = 10.0f;
constexpr float LAMBDA_NOOBJ = 0.5f;

__device__ __forceinline__ void stage16(const float* g, float* lds_uniform) {
    // width-16: per-lane global src, wave-uniform LDS dst (HW adds lane*16B)
    __builtin_amdgcn_global_load_lds(
        (const __attribute__((address_space(1))) unsigned int*)g,
        (__attribute__((address_space(3))) unsigned int*)lds_uniform,
        16, 0, 0);
}
__device__ __forceinline__ void stage4(const float* g, float* lds_uniform) {
    // width-4: per-lane global src, wave-uniform LDS dst (HW adds lane*4B)
    __builtin_amdgcn_global_load_lds(
        (const __attribute__((address_space(1))) unsigned int*)g,
        (__attribute__((address_space(3))) unsigned int*)lds_uniform,
        4, 0, 0);
}

__device__ __forceinline__ float iou_f(float b1x, float b1y, float b1w, float b1h,
                                       float b2x, float b2y, float b2w, float b2h) {
    float cx1 = b1x * 64.f, cy1 = b1y * 64.f, hw1 = b1w * 224.f, hh1 = b1h * 224.f;
    float l1 = cx1 - hw1, t1 = cy1 - hh1, r1 = cx1 + hw1, bo1 = cy1 + hh1;
    float cx2 = b2x * 64.f, cy2 = b2y * 64.f, hw2 = b2w * 224.f, hh2 = b2h * 224.f;
    float l2 = cx2 - hw2, t2 = cy2 - hh2, r2 = cx2 + hw2, bo2 = cy2 + hh2;
    float xA = fmaxf(l1, l2), yA = fmaxf(t1, t2);
    float xB = fminf(r1, r2), yB = fminf(bo1, bo2);
    float iw = fmaxf(0.f, xB - xA + 1.f);
    float ih = fmaxf(0.f, yB - yA + 1.f);
    float inter = iw * ih;
    float a1 = (r1 - l1 + 1.f) * (bo1 - t1 + 1.f);
    float a2 = (r2 - l2 + 1.f) * (bo2 - t2 + 1.f);
    return inter / (a1 + a2 - inter);
}

__device__ __forceinline__ float row_loss(const float* lds_p, const float* lds_t, int row) {
    const float2* pr = reinterpret_cast<const float2*>(lds_p + row * C);
    const float2* tr = reinterpret_cast<const float2*>(lds_t + row * C);

    float2 p01 = pr[0], p23 = pr[1], p45 = pr[2], p67 = pr[3], p89 = pr[4];
    float2 t01 = tr[0], t23 = tr[1], t45 = tr[2], t67 = tr[3], t89 = tr[4];

    float cls = 0.f;
    #pragma unroll
    for (int j = 5; j < 13; ++j) {
        float2 a = pr[j], b = tr[j];
        float dx = a.x - b.x, dy = a.y - b.y;
        cls = fmaf(dx, dx, cls);
        cls = fmaf(dy, dy, cls);
    }

    float obj   = t45.x;
    float noobj = 1.f - obj;

    float iou1 = iou_f(p01.x, p01.y, p23.x, p23.y, t01.x, t01.y, t23.x, t23.y);
    float iou2 = iou_f(p45.y, p67.x, p67.y, p89.x, t01.x, t01.y, t23.x, t23.y);

    bool  best2 = iou2 > iou1;
    float iou_m = best2 ? iou2 : iou1;

    float vpx = best2 ? p45.y : p01.x;
    float vpy = best2 ? p67.x : p01.y;
    float vpw = best2 ? p67.y : p23.x;
    float vph = best2 ? p89.x : p23.y;
    float vpc = best2 ? p89.y : p45.x;
    float vtx = best2 ? t45.y : t01.x;
    float vty = best2 ? t67.x : t01.y;
    float vtw = best2 ? t67.y : t23.x;
    float vth = best2 ? t89.x : t23.y;

    float dx = vpx - vtx, dy = vpy - vty;
    float xy = dx * dx + dy * dy;
    float sw = sqrtf(vpw) - sqrtf(vtw);
    float sh = sqrtf(vph) - sqrtf(vth);
    float wh = sw * sw + sh * sh;
    float dc = vpc - iou_m;
    float oc = dc * dc;
    float d1 = p45.x - t45.x;
    float d2 = p89.y - t89.y;

    return obj * (LAMBDA_LOC * (xy + wh) + oc + 2.f * cls)
         + LAMBDA_NOOBJ * noobj * (d1 * d1 + d2 * d2);
}

// Wave-private staging: wave w stages and consumes exactly its own 64 rows.
// No __syncthreads between staging and compute — only wave-level vmcnt(0).
// Per-block partial written to d_ws (NO same-address atomics — R5's poison).
// rows must be a multiple of BLOCK_ROWS (802816 = 3136*256).
__global__ __launch_bounds__(THREADS) void yolo_main(
    const float* __restrict__ pred, const float* __restrict__ targ,
    float* __restrict__ partial)
{
    __shared__ float lp[4][WAVE_FLOATS];
    __shared__ float lt[4][WAVE_FLOATS];

    const int tid  = threadIdx.x;
    const int wid  = tid >> 6;
    const int lane = tid & 63;

    const size_t wave_base = ((size_t)blockIdx.x * 4 + wid) * WAVE_FLOATS;
    const float* pw = pred + wave_base;
    const float* tw = targ + wave_base;

    // ---- stage this wave's 64 rows (6656 B per input) ----
    #pragma unroll
    for (int k = 0; k < 6; ++k) {
        int src = (k * 64 + lane) * 4;         // per-lane float index
        stage16(pw + src, &lp[wid][k * 256]);  // wave-uniform dst
        stage16(tw + src, &lt[wid][k * 256]);
    }
    #pragma unroll
    for (int m = 0; m < 2; ++m) {              // tail floats [1536,1664)
        int src = 1536 + m * 64 + lane;
        stage4(pw + src, &lp[wid][1536 + m * 64]);
        stage4(tw + src, &lt[wid][1536 + m * 64]);
    }

    // wave-level completion: wait only this wave's 16 loads, no block barrier
    asm volatile("s_waitcnt vmcnt(0)" ::: "memory");
    __builtin_amdgcn_sched_barrier(0);

    // ---- compute: lane owns row `lane` of its wave's region ----
    float acc = row_loss(lp[wid], lt[wid], lane);

    // ---- reduce: wave shuffle -> one barrier -> one partial per block ----
    #pragma unroll
    for (int off = 32; off > 0; off >>= 1)
        acc += __shfl_down(acc, off);

    __shared__ float wsum[4];
    if (lane == 0) wsum[wid] = acc;
    __syncthreads();
    if (tid == 0)
        partial[blockIdx.x] = wsum[0] + wsum[1] + wsum[2] + wsum[3];
}

// Single-block final reduce: n is a multiple of 4 (3136 = 784*4).
__global__ __launch_bounds__(1024) void yolo_reduce(
    const float* __restrict__ partial, float* __restrict__ out, int n4)
{
    const float4* p4 = reinterpret_cast<const float4*>(partial);
    float acc = 0.f;
    for (int i = threadIdx.x; i < n4; i += 1024) {
        float4 v = p4[i];
        acc += (v.x + v.y) + (v.z + v.w);
    }
    #pragma unroll
    for (int off = 32; off > 0; off >>= 1)
        acc += __shfl_down(acc, off);
    __shared__ float wsum[16];
    int lane = threadIdx.x & 63, wid = threadIdx.x >> 6;
    if (lane == 0) wsum[wid] = acc;
    __syncthreads();
    if (threadIdx.x == 0) {
        float s = 0.f;
        #pragma unroll
        for (int w = 0; w < 16; ++w) s += wsum[w];
        out[0] = s;
    }
}

extern "C" void kernel_launch(void* const* d_in, const int* in_sizes, int n_in,
                              void* d_out, int out_size, void* d_ws, size_t ws_size,
                              hipStream_t stream) {
    const float* pred = (const float*)d_in[0];
    const float* targ = (const float*)d_in[1];
    float* out = (float*)d_out;
    float* partial = (float*)d_ws;           // n_blocks floats of scratch
    int rows = in_sizes[0] / C;              // 802816
    int n_blocks = rows / BLOCK_ROWS;        // 3136 (exact)

    yolo_main<<<n_blocks, THREADS, 0, stream>>>(pred, targ, partial);
    yolo_reduce<<<1, 1024, 0, stream>>>(partial, out, n_blocks / 4);
}